// Round 7
// baseline (388.081 us; speedup 1.0000x reference)
//
#include <hip/hip_runtime.h>
#include <stdint.h>

#define B_BATCH 64
#define L_SEQ 2048
#define E_DIM 1024
#define A_DIM 512

typedef __attribute__((ext_vector_type(4))) float f32x4;
typedef __attribute__((ext_vector_type(8))) short bf16x8;
typedef __attribute__((ext_vector_type(2))) unsigned int u32x2;
typedef __attribute__((ext_vector_type(4))) unsigned int u32x4;

__device__ __forceinline__ unsigned short f2bf(float f) {
  unsigned u = __float_as_uint(f);
  u = (u + 0x7fffu + ((u >> 16) & 1u)) >> 16;  // RNE
  return (unsigned short)u;
}

__device__ __forceinline__ u32x2 packbf(f32x4 v) {
  u32x2 r;
  r.x = (unsigned)f2bf(v.x) | ((unsigned)f2bf(v.y) << 16);
  r.y = (unsigned)f2bf(v.z) | ((unsigned)f2bf(v.w) << 16);
  return r;
}

// A-tile LDS image per 32-k chunk: 128 rows x 64 B. 16B slot s of row n at s ^ ((n>>1)&3).
// Slot g holds k {4g..4g+3, 16+4g..16+4g+3} (proven R1-R6). BK=64 buffer = 2 chunks = 16 KB.
#define CHUNKB 8192
#define BUFB 16384          // one BK=64 buffer (2 chunks)
#define BCHUNK 32768        // ws_B bytes per 32-k chunk (512 cols x 64 B frag-chunks)
#define BCOPY (32 * BCHUNK) // 1 MB per XCD copy

// ---------------- K0: We_w (fp32 [1024,512]) -> ws_B bf16 frag image, replicated x8 --------
__global__ void prep_we_kernel(const float* __restrict__ We, char* __restrict__ wsB) {
  int t = blockIdx.x * 256 + threadIdx.x;  // 65536 threads = 1 16B chunk each
  int lane = t & 63;
  int colblk = (t >> 6) & 31;
  int step = t >> 11;  // 0..31
  int nl = lane & 15, g = lane >> 4;
  int col = colblk * 16 + nl;
  int k0 = step * 32 + 4 * g;
  unsigned q0 = (unsigned)f2bf(We[(size_t)(k0 + 0) * A_DIM + col]) |
                ((unsigned)f2bf(We[(size_t)(k0 + 1) * A_DIM + col]) << 16);
  unsigned q1 = (unsigned)f2bf(We[(size_t)(k0 + 2) * A_DIM + col]) |
                ((unsigned)f2bf(We[(size_t)(k0 + 3) * A_DIM + col]) << 16);
  unsigned q2 = (unsigned)f2bf(We[(size_t)(k0 + 16) * A_DIM + col]) |
                ((unsigned)f2bf(We[(size_t)(k0 + 17) * A_DIM + col]) << 16);
  unsigned q3 = (unsigned)f2bf(We[(size_t)(k0 + 18) * A_DIM + col]) |
                ((unsigned)f2bf(We[(size_t)(k0 + 19) * A_DIM + col]) << 16);
  u32x4 v; v.x = q0; v.y = q1; v.z = q2; v.w = q3;
#pragma unroll
  for (int c = 0; c < 8; ++c)
    *(u32x4*)(wsB + (size_t)c * BCOPY + (size_t)t * 16) = v;
}

// ---------------- K1: dcomb[b][a] = decoder_hidden[b]·Wd_w[:,a] + Wd_b[a] + We_b[a] --------
__global__ void dec_comb_kernel(const float* __restrict__ dh, const float* __restrict__ Wd,
                                const float* __restrict__ Wdb, const float* __restrict__ Web,
                                float* __restrict__ dcomb) {
  __shared__ float sh[1024];
  const int b = blockIdx.x, tid = threadIdx.x;
  for (int i = tid; i < 1024; i += 256) sh[i] = dh[b * 1024 + i];
  __syncthreads();
  const int a = blockIdx.y * 256 + tid;
  float acc = Wdb[a] + Web[a];
#pragma unroll 4
  for (int e = 0; e < 1024; ++e) acc += sh[e] * Wd[(size_t)e * A_DIM + a];
  dcomb[b * A_DIM + a] = acc;
}

// ---------------- K2: fused score GEMM, BK=64, one barrier per 64-k, local-XCD B -----------
// block: 128 rows x 512 cols, 8 waves, wave = 128x64. 16 iterations.
// Per iter: MFMA c0 (32) || loads; one WRITE_A + one s_barrier; MFMA c1 (32) after barrier.
// Hand vmcnt ledger (entry invariant [B(t,c0)=4, A(t+1)=4]):
//   +B(t,c1) -> 12; vmcnt(8) retires B(t,c0).
//   +B(t+1,c0) -> 12; vmcnt(4) retires A(t+1), B(t,c1); WRITE_A; +A(t+2) -> 8. QED.
__global__ __launch_bounds__(512, 2) void score_gemm_kernel(
    const float* __restrict__ enc, const char* __restrict__ wsB,
    const float* __restrict__ dcomb, const float* __restrict__ wf,
    float* __restrict__ scoreOut) {
  __shared__ __align__(16) char smem[3 * BUFB];
  __shared__ float s_score[128];

  const int tid = threadIdx.x;
  const int lane = tid & 63;
  const int w = tid >> 6;      // 0..7
  const int g = lane >> 4;
  const int nl = lane & 15;
  const int gs = g ^ ((nl >> 1) & 3);   // swizzled read slot

  const int row0 = (int)blockIdx.x * 128;
  const int bb = row0 >> 11;

  if (tid < 128) s_score[tid] = 0.0f;

  const float* encA = enc + (size_t)row0 * E_DIM;

  int aoff[8];
#pragma unroll
  for (int rt = 0; rt < 8; ++rt) aoff[rt] = (rt * 16 + nl) * 64 + gs * 16;

  // A staging: lane -> (row ar = tid>>2, slot c = tid&3). Per BK=64 iter loads 4 f32x4:
  // j=0,1 -> chunk0 k {4c..4c+3},{16+4c..}; j=2,3 -> chunk1 same. Writes 2x b128.
  const int ar = tid >> 2, ac = tid & 3;
  const int aw = ar * 64 + ((ac ^ ((ar >> 1) & 3)) * 16);
  const float* asrc = encA + (size_t)ar * E_DIM + ac * 4;

  // B frags from the local-XCD copy: wave w reads 4 chunks of 1 KB per 32-k chunk.
  const char* bsrc = wsB + (size_t)(blockIdx.x & 7) * BCOPY + (w * 4) * 1024 + lane * 16;

  f32x4 acc[8][4];
#pragma unroll
  for (int rt = 0; rt < 8; ++rt)
#pragma unroll
    for (int ct = 0; ct < 4; ++ct) {
      f32x4 z = {0.f, 0.f, 0.f, 0.f};
      acc[rt][ct] = z;
    }
  f32x4 ra[4];          // one BK=64 step of A (single slot)
  bf16x8 bfr0[4], bfr1[4];

#define LOAD_A(t_)                                                       \
  do {                                                                   \
    _Pragma("unroll") for (int j = 0; j < 4; ++j)                        \
        ra[j] = *(const f32x4*)(asrc + (size_t)(t_) * 64 + j * 16);      \
  } while (0)

#define LOAD_B(kc_, dst_)                                                \
  do {                                                                   \
    _Pragma("unroll") for (int ct = 0; ct < 4; ++ct) dst_[ct] =          \
        *(const bf16x8*)(bsrc + (size_t)(kc_)*BCHUNK + ct * 1024);       \
  } while (0)

#define WRITE_A(dst_)                                                    \
  do {                                                                   \
    u32x2 l0 = packbf(ra[0]), h0 = packbf(ra[1]);                        \
    u32x2 l1 = packbf(ra[2]), h1 = packbf(ra[3]);                        \
    u32x4 w0; w0.x = l0.x; w0.y = l0.y; w0.z = h0.x; w0.w = h0.y;        \
    u32x4 w1; w1.x = l1.x; w1.y = l1.y; w1.z = h1.x; w1.w = h1.y;        \
    *(u32x4*)(smem + (dst_) + aw) = w0;                                  \
    *(u32x4*)(smem + (dst_) + CHUNKB + aw) = w1;                         \
  } while (0)

#define MFMA_CHUNK(cur_, bfr_)                                           \
  do {                                                                   \
    bf16x8 afr[8];                                                       \
    _Pragma("unroll") for (int rt = 0; rt < 8; ++rt) afr[rt] =           \
        *(const bf16x8*)(smem + (cur_) + aoff[rt]);                      \
    __builtin_amdgcn_s_setprio(1);                                       \
    _Pragma("unroll") for (int rt = 0; rt < 8; ++rt)                     \
        _Pragma("unroll") for (int ct = 0; ct < 4; ++ct) acc[rt][ct] =   \
            __builtin_amdgcn_mfma_f32_16x16x32_bf16(afr[rt], bfr_[ct],   \
                                                    acc[rt][ct], 0, 0, 0); \
    __builtin_amdgcn_s_setprio(0);                                       \
  } while (0)

  // ---- prologue: establish entry invariant [B(0,c0)=4, A(1)=4], buf0 = A-step 0
  LOAD_A(0);
  LOAD_B(0, bfr0);
  asm volatile("s_waitcnt vmcnt(4)" ::: "memory");  // A(0) done
  WRITE_A(0);
  LOAD_A(1);
  asm volatile("s_waitcnt lgkmcnt(0)" ::: "memory");
  asm volatile("s_barrier" ::: "memory");

  int b0 = 0, b1 = BUFB, b2 = 2 * BUFB;
#pragma unroll 2
  for (int t = 0; t < 14; ++t) {
    LOAD_B(2 * t + 1, bfr1);                          // -> [Bc0, A(t+1), Bc1] = 12
    asm volatile("s_waitcnt vmcnt(8)" ::: "memory");  // B(t,c0) done
    MFMA_CHUNK(b0, bfr0);
    LOAD_B(2 * t + 2, bfr0);                          // -> [A(t+1), Bc1, Bn] = 12
    asm volatile("s_waitcnt vmcnt(4)" ::: "memory");  // A(t+1), B(t,c1) done
    WRITE_A(b1);
    LOAD_A(t + 2);                                    // -> [Bn, A(t+2)] = 8
    asm volatile("s_waitcnt lgkmcnt(0)" ::: "memory");
    asm volatile("s_barrier" ::: "memory");
    MFMA_CHUNK(b0 + CHUNKB, bfr1);
    int tmp = b0; b0 = b1; b1 = b2; b2 = tmp;
  }
  // ---- t = 14: no LOAD_A(16)
  LOAD_B(29, bfr1);
  asm volatile("s_waitcnt vmcnt(8)" ::: "memory");
  MFMA_CHUNK(b0, bfr0);
  LOAD_B(30, bfr0);
  asm volatile("s_waitcnt vmcnt(4)" ::: "memory");    // A(15), B(14,c1) done
  WRITE_A(b1);
  asm volatile("s_waitcnt lgkmcnt(0)" ::: "memory");
  asm volatile("s_barrier" ::: "memory");
  MFMA_CHUNK(b0 + CHUNKB, bfr1);
  { int tmp = b0; b0 = b1; b1 = b2; b2 = tmp; }
  // ---- t = 15: pending entry [B(15,c0)] = 4
  LOAD_B(31, bfr1);
  asm volatile("s_waitcnt vmcnt(4)" ::: "memory");    // B(15,c0) done
  MFMA_CHUNK(b0, bfr0);
  asm volatile("s_waitcnt vmcnt(0)" ::: "memory");    // B(15,c1) done
  MFMA_CHUNK(b0 + CHUNKB, bfr1);

#undef LOAD_A
#undef LOAD_B
#undef WRITE_A
#undef MFMA_CHUNK

  // epilogue: h = relu(acc + db), p = h·wf, reduce over 512 cols
  float db[4], wv[4];
#pragma unroll
  for (int ct = 0; ct < 4; ++ct) {
    int a = w * 64 + ct * 16 + nl;
    db[ct] = dcomb[bb * A_DIM + a];
    wv[ct] = wf[a];
  }
#pragma unroll
  for (int rt = 0; rt < 8; ++rt) {
#pragma unroll
    for (int r = 0; r < 4; ++r) {
      float p = 0.f;
#pragma unroll
      for (int ct = 0; ct < 4; ++ct) {
        float h = acc[rt][ct][r] + db[ct];
        h = h > 0.f ? h : 0.f;
        p += h * wv[ct];
      }
      p += __shfl_xor(p, 1);
      p += __shfl_xor(p, 2);
      p += __shfl_xor(p, 4);
      p += __shfl_xor(p, 8);
      if (nl == 0) atomicAdd(&s_score[rt * 16 + g * 4 + r], p);
    }
  }
  __syncthreads();
  if (tid < 128) scoreOut[row0 + tid] = s_score[tid];
}

// ---------------- K3: softmax over L per batch, in place -----------------------------------
__global__ void softmax_kernel(float* __restrict__ attn) {
  __shared__ float red[8];
  const int b = blockIdx.x, tid = threadIdx.x;
  float* p = attn + b * L_SEQ;
  float v[8];
  float m = -1e30f;
#pragma unroll
  for (int i = 0; i < 8; ++i) {
    v[i] = p[tid + i * 256];
    m = fmaxf(m, v[i]);
  }
#pragma unroll
  for (int off = 1; off < 64; off <<= 1) m = fmaxf(m, __shfl_xor(m, off));
  const int wid = tid >> 6;
  if ((tid & 63) == 0) red[wid] = m;
  __syncthreads();
  m = fmaxf(fmaxf(red[0], red[1]), fmaxf(red[2], red[3]));
  float s = 0.f;
#pragma unroll
  for (int i = 0; i < 8; ++i) {
    v[i] = __expf(v[i] - m);
    s += v[i];
  }
#pragma unroll
  for (int off = 1; off < 64; off <<= 1) s += __shfl_xor(s, off);
  __syncthreads();
  if ((tid & 63) == 0) red[4 + wid] = s;
  __syncthreads();
  const float inv = 1.0f / (red[4] + red[5] + red[6] + red[7]);
#pragma unroll
  for (int i = 0; i < 8; ++i) p[tid + i * 256] = v[i] * inv;
}

// ---------------- K4: weighted[b][e] = sum_l alpha[b][l] * enc[b][l][e] --------------------
__global__ void weighted_kernel(const float* __restrict__ enc, const float* __restrict__ alpha,
                                float* __restrict__ outW) {
  __shared__ float sa[64];
  const int bid = blockIdx.x;  // 2048 = 64 b * 32 l-segments of 64
  const int b = bid >> 5, ls = bid & 31;
  const int tid = threadIdx.x;
  if (tid < 64) sa[tid] = alpha[b * L_SEQ + ls * 64 + tid];
  __syncthreads();
  const f32x4* ep = (const f32x4*)(enc + ((size_t)(b * L_SEQ + ls * 64)) * E_DIM) + tid;
  f32x4 acc = {0.f, 0.f, 0.f, 0.f};
#pragma unroll 8
  for (int il = 0; il < 64; ++il) {
    f32x4 v = ep[(size_t)il * 256];
    float al = sa[il];
    acc.x += al * v.x;
    acc.y += al * v.y;
    acc.z += al * v.z;
    acc.w += al * v.w;
  }
  float* o = outW + b * E_DIM + tid * 4;
  atomicAdd(o + 0, acc.x);
  atomicAdd(o + 1, acc.y);
  atomicAdd(o + 2, acc.z);
  atomicAdd(o + 3, acc.w);
}

extern "C" void kernel_launch(void* const* d_in, const int* in_sizes, int n_in,
                              void* d_out, int out_size, void* d_ws, size_t ws_size,
                              hipStream_t stream) {
  const float* enc = (const float*)d_in[0];
  const float* dh = (const float*)d_in[1];
  const float* WeW = (const float*)d_in[2];
  const float* WeB = (const float*)d_in[3];
  const float* WdW = (const float*)d_in[4];
  const float* WdB = (const float*)d_in[5];
  const float* WfW = (const float*)d_in[6];
  // Wf_b (d_in[7]) irrelevant: softmax is shift-invariant and attn isn't an output.

  float* out = (float*)d_out;
  float* outW = out;                      // weighted: 64*1024
  float* attn = out + B_BATCH * E_DIM;    // scores -> alpha: 64*2048

  char* wsB = (char*)d_ws;                                       // 8 copies x 1 MB
  float* dcomb = (float*)((char*)d_ws + 8 * (size_t)BCOPY);      // 64*512 fp32

  if (ws_size < 8 * (size_t)BCOPY + (size_t)B_BATCH * A_DIM * sizeof(float)) return;

  hipMemsetAsync(outW, 0, (size_t)(B_BATCH * E_DIM) * sizeof(float), stream);
  prep_we_kernel<<<256, 256, 0, stream>>>(WeW, wsB);
  dec_comb_kernel<<<dim3(B_BATCH, 2), 256, 0, stream>>>(dh, WdW, WdB, WeB, dcomb);
  score_gemm_kernel<<<(B_BATCH * L_SEQ) / 128, 512, 0, stream>>>(enc, wsB, dcomb, WfW, attn);
  softmax_kernel<<<B_BATCH, 256, 0, stream>>>(attn);
  weighted_kernel<<<B_BATCH * 32, 256, 0, stream>>>(enc, attn, outW);
}